// Round 2
// baseline (423.965 us; speedup 1.0000x reference)
//
#include <hip/hip_runtime.h>
#include <hip/hip_bf16.h>

typedef unsigned short u16;
typedef __attribute__((ext_vector_type(8))) short bf16x8;
typedef __attribute__((ext_vector_type(4))) float f32x4;

// B=1, T=2048, DIM=2048, H=16, KV=4, HD=128
#define T_SEQ 2048
#define DIM   2048
#define NH    16
#define NKV   4
#define HD    128
#define SCALE 0.08838834764831845f  // 1/sqrt(128)

__device__ __forceinline__ u16 f2bf(float f) {
  unsigned int u = __float_as_uint(f);
  unsigned int r = (u + 0x7fffu + ((u >> 16) & 1u)) >> 16;
  return (u16)r;
}

// ---------------- cast fp32 -> bf16 (vectorized) ----------------
__global__ void cast_bf16(const float4* __restrict__ in, u16* __restrict__ out, int n4) {
  int i = blockIdx.x * blockDim.x + threadIdx.x;
  if (i < n4) {
    float4 v = in[i];
    ushort4 o;
    o.x = f2bf(v.x); o.y = f2bf(v.y); o.z = f2bf(v.z); o.w = f2bf(v.w);
    ((ushort4*)out)[i] = o;
  }
}

// ---------------- GEMM: C(M,N) = A(M,K) @ W(N,K)^T, bf16 in, fp32 out ------
// 128x128 tile, BK=64, 4 waves (2x2 of 64x64), mfma_f32_16x16x32_bf16
#define BM 128
#define BN 128
#define BK 64
#define LDP 72   // padded LDS pitch (elements)

__global__ __launch_bounds__(256) void gemm_bt(
    const u16* __restrict__ A, const u16* __restrict__ W,
    float* __restrict__ C, int M, int N, int K)
{
  __shared__ u16 As[BM * LDP];
  __shared__ u16 Bs[BN * LDP];
  const int tid  = threadIdx.x;
  const int lane = tid & 63;
  const int wave = tid >> 6;
  const int ln   = lane & 15;
  const int quad = lane >> 4;
  const int m0 = blockIdx.y * BM;
  const int n0 = blockIdx.x * BN;
  const int wm = (wave >> 1) * 64;
  const int wn = (wave & 1) * 64;

  const int sr = tid >> 3;        // 0..31
  const int sc = (tid & 7) * 8;   // 0,8,...,56

  f32x4 acc[4][4] = {};

  for (int k0 = 0; k0 < K; k0 += BK) {
#pragma unroll
    for (int c = 0; c < 4; ++c) {
      int row = c * 32 + sr;
      *(bf16x8*)&As[row * LDP + sc] =
          *(const bf16x8*)&A[(size_t)(m0 + row) * K + k0 + sc];
      *(bf16x8*)&Bs[row * LDP + sc] =
          *(const bf16x8*)&W[(size_t)(n0 + row) * K + k0 + sc];
    }
    __syncthreads();
#pragma unroll
    for (int ks = 0; ks < 2; ++ks) {
      bf16x8 af[4], bfr[4];
#pragma unroll
      for (int mt = 0; mt < 4; ++mt)
        af[mt] = *(const bf16x8*)&As[(wm + mt * 16 + ln) * LDP + ks * 32 + quad * 8];
#pragma unroll
      for (int nt = 0; nt < 4; ++nt)
        bfr[nt] = *(const bf16x8*)&Bs[(wn + nt * 16 + ln) * LDP + ks * 32 + quad * 8];
#pragma unroll
      for (int mt = 0; mt < 4; ++mt)
#pragma unroll
        for (int nt = 0; nt < 4; ++nt)
          acc[mt][nt] = __builtin_amdgcn_mfma_f32_16x16x32_bf16(
              af[mt], bfr[nt], acc[mt][nt], 0, 0, 0);
    }
    __syncthreads();
  }

#pragma unroll
  for (int mt = 0; mt < 4; ++mt)
#pragma unroll
    for (int nt = 0; nt < 4; ++nt)
#pragma unroll
      for (int r = 0; r < 4; ++r) {
        int row = m0 + wm + mt * 16 + quad * 4 + r;
        int col = n0 + wn + nt * 16 + ln;
        C[(size_t)row * N + col] = acc[mt][nt][r];
      }
}

// ---------------- RoPE (fp32 in, bf16 out) ----------------
// in: (T, NHx, HD) fp32; out same shape bf16
__global__ void rope_bf16(const float* __restrict__ in,
                          const float* __restrict__ cosT,
                          const float* __restrict__ sinT,
                          u16* __restrict__ out, int nh)
{
  int b = blockIdx.x;            // t*nh + h
  int t = b / nh;
  int d = threadIdx.x;           // 0..127
  const float* row = in + (size_t)b * HD;
  float u = row[d];
  float pr = (d < 64) ? -row[d + 64] : row[d - 64];
  float c = cosT[t * HD + d];
  float s = sinT[t * HD + d];
  out[(size_t)b * HD + d] = f2bf(u * c + pr * s);
}

// ---------------- V transpose: (T, NKV, HD) fp32 -> (NKV, HD, T) bf16 ------
__global__ void transpose_v(const float* __restrict__ Vf, u16* __restrict__ Vtb) {
  int idx = blockIdx.x * 256 + threadIdx.x;   // over NKV*HD*T
  int t = idx & (T_SEQ - 1);
  int rem = idx >> 11;          // /2048
  int d = rem & (HD - 1);
  int g = rem >> 7;
  Vtb[idx] = f2bf(Vf[((size_t)t * NKV + g) * HD + d]);
}

// ---------------- Flash attention ----------------
// grid: (T/64, NH); block 256 (4 waves, 16 q-rows each)
// Qb: (T, NH, HD) bf16 (post-rope); Kb: (T, NKV, HD) bf16 (post-rope)
// Vtb: (NKV, HD, T) bf16; AO: (T, NH*HD) bf16
#define KP 136   // Ks pitch
#define VP 72    // Vs pitch
#define PP 72    // Ps pitch

__global__ __launch_bounds__(256) void flash_attn(
    const u16* __restrict__ Qb, const u16* __restrict__ Kb,
    const u16* __restrict__ Vtb, u16* __restrict__ AO)
{
  __shared__ u16 Ks[64 * KP];        // keys x dims
  __shared__ u16 Vs[HD * VP];        // dims x keys
  __shared__ u16 Ps[4][16 * PP];     // per-wave P (16 rows x 64 keys)

  const int h  = blockIdx.y;
  const int g  = h >> 2;
  const int q0 = blockIdx.x * 64;
  const int tid  = threadIdx.x;
  const int lane = tid & 63;
  const int wave = tid >> 6;
  const int ln   = lane & 15;
  const int quad = lane >> 4;
  const int qrow_base = q0 + wave * 16 + quad * 4;

  // Q fragments (A-layout), kept in regs for the whole kernel
  bf16x8 aq[4];
  {
    const u16* qp = Qb + ((size_t)(q0 + wave * 16 + ln) * NH + h) * HD + quad * 8;
#pragma unroll
    for (int ks = 0; ks < 4; ++ks) aq[ks] = *(const bf16x8*)&qp[ks * 32];
  }

  f32x4 o[8] = {};
  float m_prev[4] = {-1e30f, -1e30f, -1e30f, -1e30f};
  float l_run[4] = {0.f, 0.f, 0.f, 0.f};

  const int ntiles = blockIdx.x + 1;
  for (int it = 0; it < ntiles; ++it) {
    const int jb = it * 64;
    // stage K tile: 64 keys x 128 dims
    {
      int r = tid >> 4, cchunk = (tid & 15) * 8;
#pragma unroll
      for (int c = 0; c < 4; ++c) {
        int row = c * 16 + r;
        *(bf16x8*)&Ks[row * KP + cchunk] =
            *(const bf16x8*)&Kb[((size_t)(jb + row) * NKV + g) * HD + cchunk];
      }
    }
    // stage V^T tile: 128 dims x 64 keys
    {
      int r = tid >> 3, cchunk = (tid & 7) * 8;
#pragma unroll
      for (int c = 0; c < 4; ++c) {
        int row = c * 32 + r;
        *(bf16x8*)&Vs[row * VP + cchunk] =
            *(const bf16x8*)&Vtb[(size_t)(g * HD + row) * T_SEQ + jb + cchunk];
      }
    }
    __syncthreads();

    // scores: 16 (rows) x 64 (keys)
    f32x4 sc[4];
#pragma unroll
    for (int nb = 0; nb < 4; ++nb) {
      f32x4 s = {};
#pragma unroll
      for (int ks = 0; ks < 4; ++ks) {
        bf16x8 kf = *(const bf16x8*)&Ks[(nb * 16 + ln) * KP + ks * 32 + quad * 8];
        s = __builtin_amdgcn_mfma_f32_16x16x32_bf16(aq[ks], kf, s, 0, 0, 0);
      }
      sc[nb] = s;
    }
    // scale + causal mask
#pragma unroll
    for (int nb = 0; nb < 4; ++nb) {
      int j = jb + nb * 16 + ln;
#pragma unroll
      for (int r = 0; r < 4; ++r) {
        float v = sc[nb][r] * SCALE;
        sc[nb][r] = (j <= qrow_base + r) ? v : -1e30f;
      }
    }
    // row max (across nb, then across the 16 lanes holding this row)
    float mx[4];
#pragma unroll
    for (int r = 0; r < 4; ++r) {
      float m = sc[0][r];
#pragma unroll
      for (int nb = 1; nb < 4; ++nb) m = fmaxf(m, sc[nb][r]);
#pragma unroll
      for (int off = 1; off < 16; off <<= 1)
        m = fmaxf(m, __shfl_xor(m, off));
      mx[r] = m;
    }
    float alpha[4];
#pragma unroll
    for (int r = 0; r < 4; ++r) {
      float mn = fmaxf(m_prev[r], mx[r]);
      alpha[r] = __expf(m_prev[r] - mn);
      m_prev[r] = mn;
    }
    // p = exp(s - m), row sum
    float rs[4] = {0.f, 0.f, 0.f, 0.f};
#pragma unroll
    for (int nb = 0; nb < 4; ++nb)
#pragma unroll
      for (int r = 0; r < 4; ++r) {
        float p = __expf(sc[nb][r] - m_prev[r]);
        sc[nb][r] = p;
        rs[r] += p;
      }
#pragma unroll
    for (int r = 0; r < 4; ++r) {
#pragma unroll
      for (int off = 1; off < 16; off <<= 1)
        rs[r] += __shfl_xor(rs[r], off);
      l_run[r] = l_run[r] * alpha[r] + rs[r];
    }
    // rescale O
#pragma unroll
    for (int nb8 = 0; nb8 < 8; ++nb8)
#pragma unroll
      for (int r = 0; r < 4; ++r) o[nb8][r] *= alpha[r];

    // P -> LDS (C-layout to A-layout round trip)
#pragma unroll
    for (int nb = 0; nb < 4; ++nb)
#pragma unroll
      for (int r = 0; r < 4; ++r)
        Ps[wave][(quad * 4 + r) * PP + nb * 16 + ln] = f2bf(sc[nb][r]);

    // O += P @ V
#pragma unroll
    for (int kst = 0; kst < 2; ++kst) {
      bf16x8 ap = *(const bf16x8*)&Ps[wave][ln * PP + kst * 32 + quad * 8];
#pragma unroll
      for (int nb8 = 0; nb8 < 8; ++nb8) {
        bf16x8 bv = *(const bf16x8*)&Vs[(nb8 * 16 + ln) * VP + kst * 32 + quad * 8];
        o[nb8] = __builtin_amdgcn_mfma_f32_16x16x32_bf16(ap, bv, o[nb8], 0, 0, 0);
      }
    }
    __syncthreads();
  }

  // epilogue: normalize, store bf16
#pragma unroll
  for (int r = 0; r < 4; ++r) {
    float inv_l = 1.0f / l_run[r];
    int row = qrow_base + r;
#pragma unroll
    for (int nb8 = 0; nb8 < 8; ++nb8) {
      int col = h * HD + nb8 * 16 + ln;
      AO[(size_t)row * DIM + col] = f2bf(o[nb8][r] * inv_l);
    }
  }
}

// ---------------- launch ----------------
// Workspace layout (peak 52 MB, reuse via stream-serialized live ranges):
//   [ 0,  8) xb        bf16 x                (live: casts .. gemm V)
//   [ 8, 16) wb        bf16 weight (REUSED: wq -> wk -> wv -> wo)
//   [16, 32) Qf fp32   (dead after rope-Q)  -- AO bf16 overlays [16,24)
//   [32, 36) Kf fp32
//   [36, 40) Vf fp32
//   [40, 48) Qb bf16
//   [48, 50) Kb bf16
//   [50, 52) Vtb bf16
extern "C" void kernel_launch(void* const* d_in, const int* in_sizes, int n_in,
                              void* d_out, int out_size, void* d_ws, size_t ws_size,
                              hipStream_t stream) {
  const float* x   = (const float*)d_in[0];  // (1, 2048, 2048)
  const float* wq  = (const float*)d_in[1];  // (2048, 2048)
  const float* wk  = (const float*)d_in[2];  // (512, 2048)
  const float* wv  = (const float*)d_in[3];  // (512, 2048)
  const float* wo  = (const float*)d_in[4];  // (2048, 2048)
  const float* cosT = (const float*)d_in[5]; // (2048, 128)
  const float* sinT = (const float*)d_in[6]; // (2048, 128)
  float* out = (float*)d_out;                // (1, 2048, 2048) fp32

  char* ws = (char*)d_ws;
  const size_t MB = 1024 * 1024;
  u16*   xb  = (u16*)(ws + 0 * MB);
  u16*   wb  = (u16*)(ws + 8 * MB);
  float* Qf  = (float*)(ws + 16 * MB);
  u16*   AO  = (u16*)(ws + 16 * MB);   // overlays Qf (Qf dead after rope-Q)
  float* Kf  = (float*)(ws + 32 * MB);
  float* Vf  = (float*)(ws + 36 * MB);
  u16*   Qb  = (u16*)(ws + 40 * MB);
  u16*   Kb  = (u16*)(ws + 48 * MB);
  u16*   Vtb = (u16*)(ws + 50 * MB);

  const int n4_x  = T_SEQ * DIM / 4;       // x and square weights
  const int n4_kv = NKV * HD * DIM / 4;    // skinny weights

  // x cast (live for all three projections)
  cast_bf16<<<(n4_x + 255) / 256, 256, 0, stream>>>((const float4*)x, xb, n4_x);

  // Q projection
  cast_bf16<<<(n4_x + 255) / 256, 256, 0, stream>>>((const float4*)wq, wb, n4_x);
  gemm_bt<<<dim3(DIM / BN, T_SEQ / BM), 256, 0, stream>>>(xb, wb, Qf, T_SEQ, DIM, DIM);
  // K projection
  cast_bf16<<<(n4_kv + 255) / 256, 256, 0, stream>>>((const float4*)wk, wb, n4_kv);
  gemm_bt<<<dim3(NKV * HD / BN, T_SEQ / BM), 256, 0, stream>>>(xb, wb, Kf, T_SEQ, NKV * HD, DIM);
  // V projection
  cast_bf16<<<(n4_kv + 255) / 256, 256, 0, stream>>>((const float4*)wv, wb, n4_kv);
  gemm_bt<<<dim3(NKV * HD / BN, T_SEQ / BM), 256, 0, stream>>>(xb, wb, Vf, T_SEQ, NKV * HD, DIM);

  // RoPE
  rope_bf16<<<T_SEQ * NH, HD, 0, stream>>>(Qf, cosT, sinT, Qb, NH);
  rope_bf16<<<T_SEQ * NKV, HD, 0, stream>>>(Kf, cosT, sinT, Kb, NKV);
  // V transpose
  transpose_v<<<(NKV * HD * T_SEQ) / 256, 256, 0, stream>>>(Vf, Vtb);

  // flash attention (writes AO, which overlays dead Qf)
  flash_attn<<<dim3(T_SEQ / 64, NH), 256, 0, stream>>>(Qb, Kb, Vtb, AO);

  // output projection
  cast_bf16<<<(n4_x + 255) / 256, 256, 0, stream>>>((const float4*)wo, wb, n4_x);
  gemm_bt<<<dim3(DIM / BN, T_SEQ / BM), 256, 0, stream>>>(AO, wb, out, T_SEQ, DIM, DIM);
}